// Round 4
// baseline (2740.533 us; speedup 1.0000x reference)
//
#include <hip/hip_runtime.h>

#define NVV 300000
#define PCNT 500000
#define EPSV 1e-5f
#define NREP 8   // replica stat buffers to spread atomic contention

// Intermediate layouts:
//   x0q : float4[16][NVV]  plane layout — plane jq holds cols 4jq..4jq+3 of x0
//   x1q : float4[8][NVV]   plane layout for x1 (32 cols)
//   proj: float [NVV][20]  row-major (k_final gathers 80B rows)
//   x2  : float [NVV][8]   row-major (k_final gathers 32B rows)

// ---------------------------------------------------------------------------
// K1: global GroupNorm stats over lv [NV,64], 32 groups x 2ch.
// ---------------------------------------------------------------------------
__global__ __launch_bounds__(256) void k_stats0(const float* __restrict__ lv,
                                                float* __restrict__ rep) {
    __shared__ float sStat[64];
    const int t = threadIdx.x;
    if (t < 64) sStat[t] = 0.f;
    __syncthreads();
    const int c4 = t & 15;
    const int sub = t >> 4;
    float s0 = 0.f, q0 = 0.f, s1 = 0.f, q1 = 0.f;
    for (int r = blockIdx.x * 16 + sub; r < NVV; r += gridDim.x * 16) {
        const float4 v = *(const float4*)(lv + (size_t)r * 64 + c4 * 4);
        s0 += v.x + v.y; q0 += v.x * v.x + v.y * v.y;
        s1 += v.z + v.w; q1 += v.z * v.z + v.w * v.w;
    }
    #pragma unroll
    for (int d = 16; d < 64; d <<= 1) {
        s0 += __shfl_xor(s0, d); q0 += __shfl_xor(q0, d);
        s1 += __shfl_xor(s1, d); q1 += __shfl_xor(q1, d);
    }
    if ((t & 63) < 16) {
        atomicAdd(&sStat[(c4 * 2) * 2 + 0], s0);
        atomicAdd(&sStat[(c4 * 2) * 2 + 1], q0);
        atomicAdd(&sStat[(c4 * 2 + 1) * 2 + 0], s1);
        atomicAdd(&sStat[(c4 * 2 + 1) * 2 + 1], q1);
    }
    __syncthreads();
    if (t < 64) atomicAdd(&rep[(blockIdx.x & (NREP - 1)) * 64 + t], sStat[t]);
}

// ---------------------------------------------------------------------------
// Finalize: sum replicas -> per-channel affine A (scale), B (shift).
// ---------------------------------------------------------------------------
__global__ void k_finalize(const float* __restrict__ rep,
                           const float* __restrict__ gw,
                           const float* __restrict__ gb,
                           float* __restrict__ A, float* __restrict__ B,
                           int C, float cntInv) {
    const int k = threadIdx.x;
    if (k >= C) return;
    const int g = (C == 32) ? k : (k >> 1);
    float s = 0.f, q = 0.f;
    #pragma unroll
    for (int r = 0; r < NREP; ++r) { s += rep[r * 64 + g * 2]; q += rep[r * 64 + g * 2 + 1]; }
    const float mean = s * cntInv;
    const float var = q * cntInv - mean * mean;
    const float rs = rsqrtf(var + EPSV);
    const float a = rs * gw[k];
    A[k] = a;
    B[k] = gb[k] - mean * a;
}

// ---------------------------------------------------------------------------
// K2: stage0.  2 rows/thread (t and t+256 of a 512-row block).  Each weight
// ds_read_b128 feeds 8 FMAs; stats butterflies amortized over both rows.
// ---------------------------------------------------------------------------
__global__ __launch_bounds__(256, 3) void k_stage0(const float* __restrict__ lv,
        const float* __restrict__ W0, const float* __restrict__ clsW,
        const float* __restrict__ A, const float* __restrict__ B,
        float4* __restrict__ x0q, float* __restrict__ proj,
        float* __restrict__ rep1) {
    __shared__ float sW[64 * 64];
    __shared__ float sC[20 * 64];
    __shared__ float sAB[128];
    __shared__ float sStat[64];
    __shared__ float sProj[256 * 20];
    const int t = threadIdx.x;
    for (int i = t; i < 64 * 64 / 4; i += 256) ((float4*)sW)[i] = ((const float4*)W0)[i];
    for (int i = t; i < 20 * 64 / 4; i += 256) ((float4*)sC)[i] = ((const float4*)clsW)[i];
    if (t < 64) { sAB[t] = A[t]; sAB[64 + t] = B[t]; sStat[t] = 0.f; }
    __syncthreads();

    const int lane = t & 63;
    const int b0 = blockIdx.x * 512;
    const int rowA = b0 + t;
    const int rowB = b0 + 256 + t;
    const bool validA = rowA < NVV;
    const bool validB = rowB < NVV;
    const int rA = validA ? rowA : NVV - 1;
    const int rB = validB ? rowB : NVV - 1;
    float vA[64], vB[64];
    {
        const float* srcA = lv + (size_t)rA * 64;
        const float* srcB = lv + (size_t)rB * 64;
        #pragma unroll
        for (int k4 = 0; k4 < 16; ++k4) {
            const float4 uA = *(const float4*)(srcA + k4 * 4);
            const float4 uB = *(const float4*)(srcB + k4 * 4);
            vA[4 * k4 + 0] = uA.x; vA[4 * k4 + 1] = uA.y; vA[4 * k4 + 2] = uA.z; vA[4 * k4 + 3] = uA.w;
            vB[4 * k4 + 0] = uB.x; vB[4 * k4 + 1] = uB.y; vB[4 * k4 + 2] = uB.z; vB[4 * k4 + 3] = uB.w;
        }
    }
    // ---- proj on RAW lv, row A -> LDS -> flush ----
    #pragma unroll
    for (int cq = 0; cq < 5; ++cq) {
        float a0 = 0.f, a1 = 0.f, a2 = 0.f, a3 = 0.f;
        #pragma unroll
        for (int k4 = 0; k4 < 16; ++k4) {
            const float v0 = vA[4 * k4], v1 = vA[4 * k4 + 1], v2 = vA[4 * k4 + 2], v3 = vA[4 * k4 + 3];
            const float4 w0 = *(const float4*)&sC[(cq * 4 + 0) * 64 + k4 * 4];
            const float4 w1 = *(const float4*)&sC[(cq * 4 + 1) * 64 + k4 * 4];
            a0 = fmaf(v0, w0.x, fmaf(v1, w0.y, fmaf(v2, w0.z, fmaf(v3, w0.w, a0))));
            a1 = fmaf(v0, w1.x, fmaf(v1, w1.y, fmaf(v2, w1.z, fmaf(v3, w1.w, a1))));
            const float4 w2 = *(const float4*)&sC[(cq * 4 + 2) * 64 + k4 * 4];
            const float4 w3 = *(const float4*)&sC[(cq * 4 + 3) * 64 + k4 * 4];
            a2 = fmaf(v0, w2.x, fmaf(v1, w2.y, fmaf(v2, w2.z, fmaf(v3, w2.w, a2))));
            a3 = fmaf(v0, w3.x, fmaf(v1, w3.y, fmaf(v2, w3.z, fmaf(v3, w3.w, a3))));
        }
        *(float4*)&sProj[t * 20 + cq * 4] = make_float4(a0, a1, a2, a3);
    }
    __syncthreads();
    {
        const int valid1 = min(256, max(0, NVV - b0));
        const int n4 = valid1 * 5;
        const float4* sp = (const float4*)sProj;
        float4* gp = (float4*)(proj + (size_t)b0 * 20);
        for (int i = t; i < n4; i += 256) gp[i] = sp[i];
    }
    __syncthreads();
    // ---- proj row B -> LDS -> flush ----
    #pragma unroll
    for (int cq = 0; cq < 5; ++cq) {
        float a0 = 0.f, a1 = 0.f, a2 = 0.f, a3 = 0.f;
        #pragma unroll
        for (int k4 = 0; k4 < 16; ++k4) {
            const float v0 = vB[4 * k4], v1 = vB[4 * k4 + 1], v2 = vB[4 * k4 + 2], v3 = vB[4 * k4 + 3];
            const float4 w0 = *(const float4*)&sC[(cq * 4 + 0) * 64 + k4 * 4];
            const float4 w1 = *(const float4*)&sC[(cq * 4 + 1) * 64 + k4 * 4];
            a0 = fmaf(v0, w0.x, fmaf(v1, w0.y, fmaf(v2, w0.z, fmaf(v3, w0.w, a0))));
            a1 = fmaf(v0, w1.x, fmaf(v1, w1.y, fmaf(v2, w1.z, fmaf(v3, w1.w, a1))));
            const float4 w2 = *(const float4*)&sC[(cq * 4 + 2) * 64 + k4 * 4];
            const float4 w3 = *(const float4*)&sC[(cq * 4 + 3) * 64 + k4 * 4];
            a2 = fmaf(v0, w2.x, fmaf(v1, w2.y, fmaf(v2, w2.z, fmaf(v3, w2.w, a2))));
            a3 = fmaf(v0, w3.x, fmaf(v1, w3.y, fmaf(v2, w3.z, fmaf(v3, w3.w, a3))));
        }
        *(float4*)&sProj[t * 20 + cq * 4] = make_float4(a0, a1, a2, a3);
    }
    __syncthreads();
    {
        const int valid2 = min(256, max(0, NVV - b0 - 256));
        const int n4 = valid2 * 5;
        const float4* sp = (const float4*)sProj;
        float4* gp = (float4*)(proj + (size_t)(b0 + 256) * 20);
        for (int i = t; i < n4; i += 256) gp[i] = sp[i];
    }
    // ---- normalize + relu both rows ----
    #pragma unroll
    for (int k4 = 0; k4 < 16; ++k4) {
        const float4 a4 = *(const float4*)&sAB[k4 * 4];
        const float4 b4 = *(const float4*)&sAB[64 + k4 * 4];
        vA[4 * k4 + 0] = fmaxf(fmaf(vA[4 * k4 + 0], a4.x, b4.x), 0.f);
        vA[4 * k4 + 1] = fmaxf(fmaf(vA[4 * k4 + 1], a4.y, b4.y), 0.f);
        vA[4 * k4 + 2] = fmaxf(fmaf(vA[4 * k4 + 2], a4.z, b4.z), 0.f);
        vA[4 * k4 + 3] = fmaxf(fmaf(vA[4 * k4 + 3], a4.w, b4.w), 0.f);
        vB[4 * k4 + 0] = fmaxf(fmaf(vB[4 * k4 + 0], a4.x, b4.x), 0.f);
        vB[4 * k4 + 1] = fmaxf(fmaf(vB[4 * k4 + 1], a4.y, b4.y), 0.f);
        vB[4 * k4 + 2] = fmaxf(fmaf(vB[4 * k4 + 2], a4.z, b4.z), 0.f);
        vB[4 * k4 + 3] = fmaxf(fmaf(vB[4 * k4 + 3], a4.w, b4.w), 0.f);
    }
    // ---- x0 = xn @ W0^T both rows -> planes; stats presummed A+B ----
    #pragma unroll
    for (int jq = 0; jq < 16; ++jq) {
        float a0 = 0.f, a1 = 0.f, a2 = 0.f, a3 = 0.f;
        float c0 = 0.f, c1 = 0.f, c2 = 0.f, c3 = 0.f;
        #pragma unroll
        for (int k4 = 0; k4 < 16; ++k4) {
            const float vA0 = vA[4 * k4], vA1 = vA[4 * k4 + 1], vA2 = vA[4 * k4 + 2], vA3 = vA[4 * k4 + 3];
            const float vB0 = vB[4 * k4], vB1 = vB[4 * k4 + 1], vB2 = vB[4 * k4 + 2], vB3 = vB[4 * k4 + 3];
            const float4 w0 = *(const float4*)&sW[(jq * 4 + 0) * 64 + k4 * 4];
            const float4 w1 = *(const float4*)&sW[(jq * 4 + 1) * 64 + k4 * 4];
            a0 = fmaf(vA0, w0.x, fmaf(vA1, w0.y, fmaf(vA2, w0.z, fmaf(vA3, w0.w, a0))));
            a1 = fmaf(vA0, w1.x, fmaf(vA1, w1.y, fmaf(vA2, w1.z, fmaf(vA3, w1.w, a1))));
            c0 = fmaf(vB0, w0.x, fmaf(vB1, w0.y, fmaf(vB2, w0.z, fmaf(vB3, w0.w, c0))));
            c1 = fmaf(vB0, w1.x, fmaf(vB1, w1.y, fmaf(vB2, w1.z, fmaf(vB3, w1.w, c1))));
            const float4 w2 = *(const float4*)&sW[(jq * 4 + 2) * 64 + k4 * 4];
            const float4 w3 = *(const float4*)&sW[(jq * 4 + 3) * 64 + k4 * 4];
            a2 = fmaf(vA0, w2.x, fmaf(vA1, w2.y, fmaf(vA2, w2.z, fmaf(vA3, w2.w, a2))));
            a3 = fmaf(vA0, w3.x, fmaf(vA1, w3.y, fmaf(vA2, w3.z, fmaf(vA3, w3.w, a3))));
            c2 = fmaf(vB0, w2.x, fmaf(vB1, w2.y, fmaf(vB2, w2.z, fmaf(vB3, w2.w, c2))));
            c3 = fmaf(vB0, w3.x, fmaf(vB1, w3.y, fmaf(vB2, w3.z, fmaf(vB3, w3.w, c3))));
        }
        if (validA) x0q[(size_t)jq * NVV + rowA] = make_float4(a0, a1, a2, a3);
        if (validB) x0q[(size_t)jq * NVV + rowB] = make_float4(c0, c1, c2, c3);
        // combined stats contributions (groups 2jq: ch0,1 / 2jq+1: ch2,3)
        float sA = (validA ? a0 + a1 : 0.f) + (validB ? c0 + c1 : 0.f);
        float qA = (validA ? a0 * a0 + a1 * a1 : 0.f) + (validB ? c0 * c0 + c1 * c1 : 0.f);
        float sB = (validA ? a2 + a3 : 0.f) + (validB ? c2 + c3 : 0.f);
        float qB = (validA ? a2 * a2 + a3 * a3 : 0.f) + (validB ? c2 * c2 + c3 * c3 : 0.f);
        #pragma unroll
        for (int d = 1; d < 64; d <<= 1) {
            sA += __shfl_xor(sA, d); qA += __shfl_xor(qA, d);
            sB += __shfl_xor(sB, d); qB += __shfl_xor(qB, d);
        }
        if (lane == 0) {
            atomicAdd(&sStat[(2 * jq) * 2 + 0], sA);
            atomicAdd(&sStat[(2 * jq) * 2 + 1], qA);
            atomicAdd(&sStat[(2 * jq + 1) * 2 + 0], sB);
            atomicAdd(&sStat[(2 * jq + 1) * 2 + 1], qB);
        }
    }
    __syncthreads();
    if (t < 64) atomicAdd(&rep1[(blockIdx.x & (NREP - 1)) * 64 + t], sStat[t]);
}

// ---------------------------------------------------------------------------
// K3: stage1.  2 rows/thread; reads x0 planes, writes x1 planes; fused stats.
// ---------------------------------------------------------------------------
__global__ __launch_bounds__(256, 3) void k_stage1(const float4* __restrict__ x0q,
        const float* __restrict__ W1,
        const float* __restrict__ A, const float* __restrict__ B,
        float4* __restrict__ x1q, float* __restrict__ rep2) {
    __shared__ float sW[32 * 64];
    __shared__ float sAB[128];
    __shared__ float sStat[64];
    const int t = threadIdx.x;
    for (int i = t; i < 32 * 64 / 4; i += 256) ((float4*)sW)[i] = ((const float4*)W1)[i];
    if (t < 64) { sAB[t] = A[t]; sAB[64 + t] = B[t]; sStat[t] = 0.f; }
    __syncthreads();

    const int lane = t & 63;
    const int b0 = blockIdx.x * 512;
    const int rowA = b0 + t;
    const int rowB = b0 + 256 + t;
    const bool validA = rowA < NVV;
    const bool validB = rowB < NVV;
    const int rA = validA ? rowA : NVV - 1;
    const int rB = validB ? rowB : NVV - 1;
    float vA[64], vB[64];
    #pragma unroll
    for (int k4 = 0; k4 < 16; ++k4) {
        const float4 uA = x0q[(size_t)k4 * NVV + rA];
        const float4 uB = x0q[(size_t)k4 * NVV + rB];
        const float4 a4 = *(const float4*)&sAB[k4 * 4];
        const float4 b4 = *(const float4*)&sAB[64 + k4 * 4];
        vA[4 * k4 + 0] = fmaxf(fmaf(uA.x, a4.x, b4.x), 0.f);
        vA[4 * k4 + 1] = fmaxf(fmaf(uA.y, a4.y, b4.y), 0.f);
        vA[4 * k4 + 2] = fmaxf(fmaf(uA.z, a4.z, b4.z), 0.f);
        vA[4 * k4 + 3] = fmaxf(fmaf(uA.w, a4.w, b4.w), 0.f);
        vB[4 * k4 + 0] = fmaxf(fmaf(uB.x, a4.x, b4.x), 0.f);
        vB[4 * k4 + 1] = fmaxf(fmaf(uB.y, a4.y, b4.y), 0.f);
        vB[4 * k4 + 2] = fmaxf(fmaf(uB.z, a4.z, b4.z), 0.f);
        vB[4 * k4 + 3] = fmaxf(fmaf(uB.w, a4.w, b4.w), 0.f);
    }
    #pragma unroll
    for (int jq = 0; jq < 8; ++jq) {
        float a0 = 0.f, a1 = 0.f, a2 = 0.f, a3 = 0.f;
        float c0 = 0.f, c1 = 0.f, c2 = 0.f, c3 = 0.f;
        #pragma unroll
        for (int k4 = 0; k4 < 16; ++k4) {
            const float vA0 = vA[4 * k4], vA1 = vA[4 * k4 + 1], vA2 = vA[4 * k4 + 2], vA3 = vA[4 * k4 + 3];
            const float vB0 = vB[4 * k4], vB1 = vB[4 * k4 + 1], vB2 = vB[4 * k4 + 2], vB3 = vB[4 * k4 + 3];
            const float4 w0 = *(const float4*)&sW[(jq * 4 + 0) * 64 + k4 * 4];
            const float4 w1 = *(const float4*)&sW[(jq * 4 + 1) * 64 + k4 * 4];
            a0 = fmaf(vA0, w0.x, fmaf(vA1, w0.y, fmaf(vA2, w0.z, fmaf(vA3, w0.w, a0))));
            a1 = fmaf(vA0, w1.x, fmaf(vA1, w1.y, fmaf(vA2, w1.z, fmaf(vA3, w1.w, a1))));
            c0 = fmaf(vB0, w0.x, fmaf(vB1, w0.y, fmaf(vB2, w0.z, fmaf(vB3, w0.w, c0))));
            c1 = fmaf(vB0, w1.x, fmaf(vB1, w1.y, fmaf(vB2, w1.z, fmaf(vB3, w1.w, c1))));
            const float4 w2 = *(const float4*)&sW[(jq * 4 + 2) * 64 + k4 * 4];
            const float4 w3 = *(const float4*)&sW[(jq * 4 + 3) * 64 + k4 * 4];
            a2 = fmaf(vA0, w2.x, fmaf(vA1, w2.y, fmaf(vA2, w2.z, fmaf(vA3, w2.w, a2))));
            a3 = fmaf(vA0, w3.x, fmaf(vA1, w3.y, fmaf(vA2, w3.z, fmaf(vA3, w3.w, a3))));
            c2 = fmaf(vB0, w2.x, fmaf(vB1, w2.y, fmaf(vB2, w2.z, fmaf(vB3, w2.w, c2))));
            c3 = fmaf(vB0, w3.x, fmaf(vB1, w3.y, fmaf(vB2, w3.z, fmaf(vB3, w3.w, c3))));
        }
        if (validA) x1q[(size_t)jq * NVV + rowA] = make_float4(a0, a1, a2, a3);
        if (validB) x1q[(size_t)jq * NVV + rowB] = make_float4(c0, c1, c2, c3);
        float s0 = (validA ? a0 : 0.f) + (validB ? c0 : 0.f);
        float q0 = (validA ? a0 * a0 : 0.f) + (validB ? c0 * c0 : 0.f);
        float s1 = (validA ? a1 : 0.f) + (validB ? c1 : 0.f);
        float q1 = (validA ? a1 * a1 : 0.f) + (validB ? c1 * c1 : 0.f);
        float s2 = (validA ? a2 : 0.f) + (validB ? c2 : 0.f);
        float q2 = (validA ? a2 * a2 : 0.f) + (validB ? c2 * c2 : 0.f);
        float s3 = (validA ? a3 : 0.f) + (validB ? c3 : 0.f);
        float q3 = (validA ? a3 * a3 : 0.f) + (validB ? c3 * c3 : 0.f);
        #pragma unroll
        for (int d = 1; d < 64; d <<= 1) {
            s0 += __shfl_xor(s0, d); q0 += __shfl_xor(q0, d);
            s1 += __shfl_xor(s1, d); q1 += __shfl_xor(q1, d);
            s2 += __shfl_xor(s2, d); q2 += __shfl_xor(q2, d);
            s3 += __shfl_xor(s3, d); q3 += __shfl_xor(q3, d);
        }
        if (lane == 0) {
            atomicAdd(&sStat[(jq * 4 + 0) * 2 + 0], s0); atomicAdd(&sStat[(jq * 4 + 0) * 2 + 1], q0);
            atomicAdd(&sStat[(jq * 4 + 1) * 2 + 0], s1); atomicAdd(&sStat[(jq * 4 + 1) * 2 + 1], q1);
            atomicAdd(&sStat[(jq * 4 + 2) * 2 + 0], s2); atomicAdd(&sStat[(jq * 4 + 2) * 2 + 1], q2);
            atomicAdd(&sStat[(jq * 4 + 3) * 2 + 0], s3); atomicAdd(&sStat[(jq * 4 + 3) * 2 + 1], q3);
        }
    }
    __syncthreads();
    if (t < 64) atomicAdd(&rep2[(blockIdx.x & (NREP - 1)) * 64 + t], sStat[t]);
}

// ---------------------------------------------------------------------------
// K4: stage2.  Reads x1 planes, writes x2 row-major [NV,8].
// ---------------------------------------------------------------------------
__global__ __launch_bounds__(256, 4) void k_stage2(const float4* __restrict__ x1q,
        const float* __restrict__ W2,
        const float* __restrict__ A, const float* __restrict__ B,
        float* __restrict__ x2) {
    __shared__ float sW[8 * 32];
    __shared__ float sAB[64];
    const int t = threadIdx.x;
    if (t < 64) ((float4*)sW)[t] = ((const float4*)W2)[t];
    if (t < 32) { sAB[t] = A[t]; sAB[32 + t] = B[t]; }
    __syncthreads();

    const int row = blockIdx.x * 256 + t;
    const bool valid = row < NVV;
    const int r = valid ? row : NVV - 1;
    float v[32];
    #pragma unroll
    for (int k4 = 0; k4 < 8; ++k4) {
        const float4 u = x1q[(size_t)k4 * NVV + r];
        const float4 a4 = *(const float4*)&sAB[k4 * 4];
        const float4 b4 = *(const float4*)&sAB[32 + k4 * 4];
        v[4 * k4 + 0] = fmaxf(fmaf(u.x, a4.x, b4.x), 0.f);
        v[4 * k4 + 1] = fmaxf(fmaf(u.y, a4.y, b4.y), 0.f);
        v[4 * k4 + 2] = fmaxf(fmaf(u.z, a4.z, b4.z), 0.f);
        v[4 * k4 + 3] = fmaxf(fmaf(u.w, a4.w, b4.w), 0.f);
    }
    #pragma unroll
    for (int jq = 0; jq < 2; ++jq) {
        float a0 = 0.f, a1 = 0.f, a2 = 0.f, a3 = 0.f;
        #pragma unroll
        for (int k4 = 0; k4 < 8; ++k4) {
            const float4 w0 = *(const float4*)&sW[(jq * 4 + 0) * 32 + k4 * 4];
            const float4 w1 = *(const float4*)&sW[(jq * 4 + 1) * 32 + k4 * 4];
            const float4 w2 = *(const float4*)&sW[(jq * 4 + 2) * 32 + k4 * 4];
            const float4 w3 = *(const float4*)&sW[(jq * 4 + 3) * 32 + k4 * 4];
            const float v0 = v[4 * k4], v1 = v[4 * k4 + 1], v2 = v[4 * k4 + 2], v3 = v[4 * k4 + 3];
            a0 = fmaf(v0, w0.x, fmaf(v1, w0.y, fmaf(v2, w0.z, fmaf(v3, w0.w, a0))));
            a1 = fmaf(v0, w1.x, fmaf(v1, w1.y, fmaf(v2, w1.z, fmaf(v3, w1.w, a1))));
            a2 = fmaf(v0, w2.x, fmaf(v1, w2.y, fmaf(v2, w2.z, fmaf(v3, w2.w, a2))));
            a3 = fmaf(v0, w3.x, fmaf(v1, w3.y, fmaf(v2, w3.z, fmaf(v3, w3.w, a3))));
        }
        if (valid) *(float4*)(x2 + (size_t)row * 8 + jq * 4) = make_float4(a0, a1, a2, a3);
    }
}

// ---------------------------------------------------------------------------
// K5: per-position gather + max-normalize + delta weights + classify via proj.
// ---------------------------------------------------------------------------
__global__ __launch_bounds__(256, 4) void k_final(const int* __restrict__ idx,
        const float* __restrict__ bary, const float* __restrict__ x2,
        const float* __restrict__ proj, const float* __restrict__ gamma,
        const float* __restrict__ beta, const float* __restrict__ dWw,
        const float* __restrict__ dWb, const float* __restrict__ clsb,
        float* __restrict__ out) {
    const int p = blockIdx.x * 256 + threadIdx.x;
    if (p >= PCNT) return;
    const int4 iv = *(const int4*)(idx + (size_t)p * 4);
    const float4 bv = *(const float4*)(bary + (size_t)p * 4);
    const int ids[4] = {iv.x, iv.y, iv.z, iv.w};
    const float bb[4] = {bv.x, bv.y, bv.z, bv.w};
    float g[4][8];
    #pragma unroll
    for (int vtx = 0; vtx < 4; ++vtx) {
        const float* s = x2 + (size_t)ids[vtx] * 8;
        const float4 u0 = *(const float4*)(s);
        const float4 u1 = *(const float4*)(s + 4);
        g[vtx][0] = u0.x; g[vtx][1] = u0.y; g[vtx][2] = u0.z; g[vtx][3] = u0.w;
        g[vtx][4] = u1.x; g[vtx][5] = u1.y; g[vtx][6] = u1.z; g[vtx][7] = u1.w;
    }
    float sub[9];
    #pragma unroll
    for (int j = 0; j < 8; ++j) {
        const float mx = fmaxf(fmaxf(g[0][j], g[1][j]), fmaxf(g[2][j], g[3][j]));
        sub[j] = fmaf(gamma[j], mx, beta[j]);
    }
    {
        const float mx8 = fmaxf(fmaxf(bb[0], bb[1]), fmaxf(bb[2], bb[3]));
        sub[8] = fmaf(gamma[8], mx8, beta[8]);
    }
    float wv4[4];
    #pragma unroll
    for (int vtx = 0; vtx < 4; ++vtx) {
        float dw = dWb[0];
        #pragma unroll
        for (int j = 0; j < 8; ++j) dw = fmaf(g[vtx][j] - sub[j], dWw[j], dw);
        dw = fmaf(bb[vtx] - sub[8], dWw[8], dw);
        wv4[vtx] = bb[vtx] + dw;
    }
    float acc[20];
    #pragma unroll
    for (int c = 0; c < 20; ++c) acc[c] = clsb[c];
    #pragma unroll
    for (int vtx = 0; vtx < 4; ++vtx) {
        const float* pr = proj + (size_t)ids[vtx] * 20;
        const float wgt = wv4[vtx];
        #pragma unroll
        for (int cq = 0; cq < 5; ++cq) {
            const float4 u = *(const float4*)(pr + cq * 4);
            acc[cq * 4 + 0] = fmaf(wgt, u.x, acc[cq * 4 + 0]);
            acc[cq * 4 + 1] = fmaf(wgt, u.y, acc[cq * 4 + 1]);
            acc[cq * 4 + 2] = fmaf(wgt, u.z, acc[cq * 4 + 2]);
            acc[cq * 4 + 3] = fmaf(wgt, u.w, acc[cq * 4 + 3]);
        }
    }
    float* o = out + (size_t)p * 20;
    #pragma unroll
    for (int cq = 0; cq < 5; ++cq)
        *(float4*)(o + cq * 4) = make_float4(acc[cq * 4 + 0], acc[cq * 4 + 1],
                                             acc[cq * 4 + 2], acc[cq * 4 + 3]);
}

// ---------------------------------------------------------------------------
extern "C" void kernel_launch(void* const* d_in, const int* in_sizes, int n_in,
                              void* d_out, int out_size, void* d_ws, size_t ws_size,
                              hipStream_t stream) {
    const float* lv   = (const float*)d_in[0];
    // d_in[1] = positions — unused by the reference
    const int*   idx  = (const int*)d_in[2];
    const float* bary = (const float*)d_in[3];
    const float* gn0w = (const float*)d_in[4];
    const float* gn0b = (const float*)d_in[5];
    const float* W0   = (const float*)d_in[6];
    const float* gn1w = (const float*)d_in[7];
    const float* gn1b = (const float*)d_in[8];
    const float* W1   = (const float*)d_in[9];
    const float* gn2w = (const float*)d_in[10];
    const float* gn2b = (const float*)d_in[11];
    const float* W2   = (const float*)d_in[12];
    const float* gamma= (const float*)d_in[13];
    const float* beta = (const float*)d_in[14];
    const float* dWw  = (const float*)d_in[15];
    const float* dWb  = (const float*)d_in[16];
    const float* clsW = (const float*)d_in[17];
    const float* clsb = (const float*)d_in[18];
    float* out = (float*)d_out;

    float* w = (float*)d_ws;
    float* rep0 = w;                  // 8*64
    float* rep1 = w + 512;            // 8*64
    float* rep2 = w + 1024;           // 8*64
    float* A0 = w + 1536; float* B0 = w + 1600;
    float* A1 = w + 1664; float* B1 = w + 1728;
    float* A2 = w + 1792; float* B2 = w + 1856;
    float*  proj = w + 2048;                         // NV*20 floats
    float4* x0q  = (float4*)(proj + (size_t)NVV * 20);   // 16*NV float4
    float4* x1q  = x0q + (size_t)16 * NVV;               // 8*NV float4
    float*  x2   = (float*)x0q;                          // reuse x0q after K3

    hipMemsetAsync(w, 0, 1536 * sizeof(float), stream);
    k_stats0<<<512, 256, 0, stream>>>(lv, rep0);
    k_finalize<<<1, 64, 0, stream>>>(rep0, gn0w, gn0b, A0, B0, 64, 1.f / (NVV * 2.f));
    k_stage0<<<586, 256, 0, stream>>>(lv, W0, clsW, A0, B0, x0q, proj, rep1);
    k_finalize<<<1, 64, 0, stream>>>(rep1, gn1w, gn1b, A1, B1, 64, 1.f / (NVV * 2.f));
    k_stage1<<<586, 256, 0, stream>>>(x0q, W1, A1, B1, x1q, rep2);
    k_finalize<<<1, 32, 0, stream>>>(rep2, gn2w, gn2b, A2, B2, 32, 1.f / (float)NVV);
    k_stage2<<<1172, 256, 0, stream>>>(x1q, W2, A2, B2, x2);
    k_final<<<1954, 256, 0, stream>>>(idx, bary, x2, proj, gamma, beta, dWw, dWb, clsb, out);
}

// Round 6
// 1908.379 us; speedup vs baseline: 1.4361x; 1.4361x over previous
//
#include <hip/hip_runtime.h>

#define NVV 300000
#define PCNT 500000
#define EPSV 1e-5f
#define NREP 8   // replica stat buffers to spread atomic contention

// Intermediate layouts:
//   x0q : float4[16][NVV]  plane layout — plane jq holds cols 4jq..4jq+3 of x0
//   x1q : float4[8][NVV]   plane layout for x1 (32 cols)
//   proj: float [NVV][20]  row-major (k_final gathers 80B rows)
//   x2  : float [NVV][8]   row-major (k_final gathers 32B rows)

// ---------------------------------------------------------------------------
// K1: global GroupNorm stats over lv [NV,64], 32 groups x 2ch.
// ---------------------------------------------------------------------------
__global__ __launch_bounds__(256) void k_stats0(const float* __restrict__ lv,
                                                float* __restrict__ rep) {
    __shared__ float sStat[64];
    const int t = threadIdx.x;
    if (t < 64) sStat[t] = 0.f;
    __syncthreads();
    const int c4 = t & 15;
    const int sub = t >> 4;
    float s0 = 0.f, q0 = 0.f, s1 = 0.f, q1 = 0.f;
    for (int r = blockIdx.x * 16 + sub; r < NVV; r += gridDim.x * 16) {
        const float4 v = *(const float4*)(lv + (size_t)r * 64 + c4 * 4);
        s0 += v.x + v.y; q0 += v.x * v.x + v.y * v.y;
        s1 += v.z + v.w; q1 += v.z * v.z + v.w * v.w;
    }
    #pragma unroll
    for (int d = 16; d < 64; d <<= 1) {
        s0 += __shfl_xor(s0, d); q0 += __shfl_xor(q0, d);
        s1 += __shfl_xor(s1, d); q1 += __shfl_xor(q1, d);
    }
    if ((t & 63) < 16) {
        atomicAdd(&sStat[(c4 * 2) * 2 + 0], s0);
        atomicAdd(&sStat[(c4 * 2) * 2 + 1], q0);
        atomicAdd(&sStat[(c4 * 2 + 1) * 2 + 0], s1);
        atomicAdd(&sStat[(c4 * 2 + 1) * 2 + 1], q1);
    }
    __syncthreads();
    if (t < 64) atomicAdd(&rep[(blockIdx.x & (NREP - 1)) * 64 + t], sStat[t]);
}

// ---------------------------------------------------------------------------
// Finalize: sum replicas -> per-channel affine A (scale), B (shift).
// ---------------------------------------------------------------------------
__global__ void k_finalize(const float* __restrict__ rep,
                           const float* __restrict__ gw,
                           const float* __restrict__ gb,
                           float* __restrict__ A, float* __restrict__ B,
                           int C, float cntInv) {
    const int k = threadIdx.x;
    if (k >= C) return;
    const int g = (C == 32) ? k : (k >> 1);
    float s = 0.f, q = 0.f;
    #pragma unroll
    for (int r = 0; r < NREP; ++r) { s += rep[r * 64 + g * 2]; q += rep[r * 64 + g * 2 + 1]; }
    const float mean = s * cntInv;
    const float var = q * cntInv - mean * mean;
    const float rs = rsqrtf(var + EPSV);
    const float a = rs * gw[k];
    A[k] = a;
    B[k] = gb[k] - mean * a;
}

// ---------------------------------------------------------------------------
// K2: stage0.  2 rows/thread (t and t+256 of a 512-row block).  Each weight
// ds_read_b128 feeds 8 FMAs.  __launch_bounds__(256,2): ~256 VGPR budget so
// vA[64]+vB[64]+acc stay register-resident (the (256,3) cap of ~170 caused a
// catastrophic spill in round 4: VGPR 84, 4.5 GB scratch traffic).
// ---------------------------------------------------------------------------
__global__ __launch_bounds__(256, 2) void k_stage0(const float* __restrict__ lv,
        const float* __restrict__ W0, const float* __restrict__ clsW,
        const float* __restrict__ A, const float* __restrict__ B,
        float4* __restrict__ x0q, float* __restrict__ proj,
        float* __restrict__ rep1) {
    __shared__ float sW[64 * 64];
    __shared__ float sC[20 * 64];
    __shared__ float sAB[128];
    __shared__ float sStat[64];
    __shared__ float sProj[256 * 20];
    const int t = threadIdx.x;
    for (int i = t; i < 64 * 64 / 4; i += 256) ((float4*)sW)[i] = ((const float4*)W0)[i];
    for (int i = t; i < 20 * 64 / 4; i += 256) ((float4*)sC)[i] = ((const float4*)clsW)[i];
    if (t < 64) { sAB[t] = A[t]; sAB[64 + t] = B[t]; sStat[t] = 0.f; }
    __syncthreads();

    const int lane = t & 63;
    const int b0 = blockIdx.x * 512;
    const int rowA = b0 + t;
    const int rowB = b0 + 256 + t;
    const bool validA = rowA < NVV;
    const bool validB = rowB < NVV;
    const int rA = validA ? rowA : NVV - 1;
    const int rB = validB ? rowB : NVV - 1;
    float vA[64];
    {
        const float* srcA = lv + (size_t)rA * 64;
        #pragma unroll
        for (int k4 = 0; k4 < 16; ++k4) {
            const float4 uA = *(const float4*)(srcA + k4 * 4);
            vA[4 * k4 + 0] = uA.x; vA[4 * k4 + 1] = uA.y; vA[4 * k4 + 2] = uA.z; vA[4 * k4 + 3] = uA.w;
        }
    }
    // ---- proj on RAW lv, row A -> LDS -> flush ----
    #pragma unroll
    for (int cq = 0; cq < 5; ++cq) {
        float a0 = 0.f, a1 = 0.f, a2 = 0.f, a3 = 0.f;
        #pragma unroll
        for (int k4 = 0; k4 < 16; ++k4) {
            const float v0 = vA[4 * k4], v1 = vA[4 * k4 + 1], v2 = vA[4 * k4 + 2], v3 = vA[4 * k4 + 3];
            const float4 w0 = *(const float4*)&sC[(cq * 4 + 0) * 64 + k4 * 4];
            const float4 w1 = *(const float4*)&sC[(cq * 4 + 1) * 64 + k4 * 4];
            a0 = fmaf(v0, w0.x, fmaf(v1, w0.y, fmaf(v2, w0.z, fmaf(v3, w0.w, a0))));
            a1 = fmaf(v0, w1.x, fmaf(v1, w1.y, fmaf(v2, w1.z, fmaf(v3, w1.w, a1))));
            const float4 w2 = *(const float4*)&sC[(cq * 4 + 2) * 64 + k4 * 4];
            const float4 w3 = *(const float4*)&sC[(cq * 4 + 3) * 64 + k4 * 4];
            a2 = fmaf(v0, w2.x, fmaf(v1, w2.y, fmaf(v2, w2.z, fmaf(v3, w2.w, a2))));
            a3 = fmaf(v0, w3.x, fmaf(v1, w3.y, fmaf(v2, w3.z, fmaf(v3, w3.w, a3))));
        }
        *(float4*)&sProj[t * 20 + cq * 4] = make_float4(a0, a1, a2, a3);
    }
    __syncthreads();
    {
        const int valid1 = min(256, max(0, NVV - b0));
        const int n4 = valid1 * 5;
        const float4* sp = (const float4*)sProj;
        float4* gp = (float4*)(proj + (size_t)b0 * 20);
        for (int i = t; i < n4; i += 256) gp[i] = sp[i];
    }
    __syncthreads();
    // ---- load row B now (keeps peak live range out of the proj-A phase) ----
    float vB[64];
    {
        const float* srcB = lv + (size_t)rB * 64;
        #pragma unroll
        for (int k4 = 0; k4 < 16; ++k4) {
            const float4 uB = *(const float4*)(srcB + k4 * 4);
            vB[4 * k4 + 0] = uB.x; vB[4 * k4 + 1] = uB.y; vB[4 * k4 + 2] = uB.z; vB[4 * k4 + 3] = uB.w;
        }
    }
    // ---- proj row B -> LDS -> flush ----
    #pragma unroll
    for (int cq = 0; cq < 5; ++cq) {
        float a0 = 0.f, a1 = 0.f, a2 = 0.f, a3 = 0.f;
        #pragma unroll
        for (int k4 = 0; k4 < 16; ++k4) {
            const float v0 = vB[4 * k4], v1 = vB[4 * k4 + 1], v2 = vB[4 * k4 + 2], v3 = vB[4 * k4 + 3];
            const float4 w0 = *(const float4*)&sC[(cq * 4 + 0) * 64 + k4 * 4];
            const float4 w1 = *(const float4*)&sC[(cq * 4 + 1) * 64 + k4 * 4];
            a0 = fmaf(v0, w0.x, fmaf(v1, w0.y, fmaf(v2, w0.z, fmaf(v3, w0.w, a0))));
            a1 = fmaf(v0, w1.x, fmaf(v1, w1.y, fmaf(v2, w1.z, fmaf(v3, w1.w, a1))));
            const float4 w2 = *(const float4*)&sC[(cq * 4 + 2) * 64 + k4 * 4];
            const float4 w3 = *(const float4*)&sC[(cq * 4 + 3) * 64 + k4 * 4];
            a2 = fmaf(v0, w2.x, fmaf(v1, w2.y, fmaf(v2, w2.z, fmaf(v3, w2.w, a2))));
            a3 = fmaf(v0, w3.x, fmaf(v1, w3.y, fmaf(v2, w3.z, fmaf(v3, w3.w, a3))));
        }
        *(float4*)&sProj[t * 20 + cq * 4] = make_float4(a0, a1, a2, a3);
    }
    __syncthreads();
    {
        const int valid2 = min(256, max(0, NVV - b0 - 256));
        const int n4 = valid2 * 5;
        const float4* sp = (const float4*)sProj;
        float4* gp = (float4*)(proj + (size_t)(b0 + 256) * 20);
        for (int i = t; i < n4; i += 256) gp[i] = sp[i];
    }
    // ---- normalize + relu both rows ----
    #pragma unroll
    for (int k4 = 0; k4 < 16; ++k4) {
        const float4 a4 = *(const float4*)&sAB[k4 * 4];
        const float4 b4 = *(const float4*)&sAB[64 + k4 * 4];
        vA[4 * k4 + 0] = fmaxf(fmaf(vA[4 * k4 + 0], a4.x, b4.x), 0.f);
        vA[4 * k4 + 1] = fmaxf(fmaf(vA[4 * k4 + 1], a4.y, b4.y), 0.f);
        vA[4 * k4 + 2] = fmaxf(fmaf(vA[4 * k4 + 2], a4.z, b4.z), 0.f);
        vA[4 * k4 + 3] = fmaxf(fmaf(vA[4 * k4 + 3], a4.w, b4.w), 0.f);
        vB[4 * k4 + 0] = fmaxf(fmaf(vB[4 * k4 + 0], a4.x, b4.x), 0.f);
        vB[4 * k4 + 1] = fmaxf(fmaf(vB[4 * k4 + 1], a4.y, b4.y), 0.f);
        vB[4 * k4 + 2] = fmaxf(fmaf(vB[4 * k4 + 2], a4.z, b4.z), 0.f);
        vB[4 * k4 + 3] = fmaxf(fmaf(vB[4 * k4 + 3], a4.w, b4.w), 0.f);
    }
    // ---- x0 = xn @ W0^T both rows -> planes; stats presummed A+B ----
    #pragma unroll
    for (int jq = 0; jq < 16; ++jq) {
        float a0 = 0.f, a1 = 0.f, a2 = 0.f, a3 = 0.f;
        float c0 = 0.f, c1 = 0.f, c2 = 0.f, c3 = 0.f;
        #pragma unroll
        for (int k4 = 0; k4 < 16; ++k4) {
            const float vA0 = vA[4 * k4], vA1 = vA[4 * k4 + 1], vA2 = vA[4 * k4 + 2], vA3 = vA[4 * k4 + 3];
            const float vB0 = vB[4 * k4], vB1 = vB[4 * k4 + 1], vB2 = vB[4 * k4 + 2], vB3 = vB[4 * k4 + 3];
            const float4 w0 = *(const float4*)&sW[(jq * 4 + 0) * 64 + k4 * 4];
            const float4 w1 = *(const float4*)&sW[(jq * 4 + 1) * 64 + k4 * 4];
            a0 = fmaf(vA0, w0.x, fmaf(vA1, w0.y, fmaf(vA2, w0.z, fmaf(vA3, w0.w, a0))));
            a1 = fmaf(vA0, w1.x, fmaf(vA1, w1.y, fmaf(vA2, w1.z, fmaf(vA3, w1.w, a1))));
            c0 = fmaf(vB0, w0.x, fmaf(vB1, w0.y, fmaf(vB2, w0.z, fmaf(vB3, w0.w, c0))));
            c1 = fmaf(vB0, w1.x, fmaf(vB1, w1.y, fmaf(vB2, w1.z, fmaf(vB3, w1.w, c1))));
            const float4 w2 = *(const float4*)&sW[(jq * 4 + 2) * 64 + k4 * 4];
            const float4 w3 = *(const float4*)&sW[(jq * 4 + 3) * 64 + k4 * 4];
            a2 = fmaf(vA0, w2.x, fmaf(vA1, w2.y, fmaf(vA2, w2.z, fmaf(vA3, w2.w, a2))));
            a3 = fmaf(vA0, w3.x, fmaf(vA1, w3.y, fmaf(vA2, w3.z, fmaf(vA3, w3.w, a3))));
            c2 = fmaf(vB0, w2.x, fmaf(vB1, w2.y, fmaf(vB2, w2.z, fmaf(vB3, w2.w, c2))));
            c3 = fmaf(vB0, w3.x, fmaf(vB1, w3.y, fmaf(vB2, w3.z, fmaf(vB3, w3.w, c3))));
        }
        if (validA) x0q[(size_t)jq * NVV + rowA] = make_float4(a0, a1, a2, a3);
        if (validB) x0q[(size_t)jq * NVV + rowB] = make_float4(c0, c1, c2, c3);
        // combined stats contributions (groups 2jq: ch0,1 / 2jq+1: ch2,3)
        float sA = (validA ? a0 + a1 : 0.f) + (validB ? c0 + c1 : 0.f);
        float qA = (validA ? a0 * a0 + a1 * a1 : 0.f) + (validB ? c0 * c0 + c1 * c1 : 0.f);
        float sB = (validA ? a2 + a3 : 0.f) + (validB ? c2 + c3 : 0.f);
        float qB = (validA ? a2 * a2 + a3 * a3 : 0.f) + (validB ? c2 * c2 + c3 * c3 : 0.f);
        #pragma unroll
        for (int d = 1; d < 64; d <<= 1) {
            sA += __shfl_xor(sA, d); qA += __shfl_xor(qA, d);
            sB += __shfl_xor(sB, d); qB += __shfl_xor(qB, d);
        }
        if (lane == 0) {
            atomicAdd(&sStat[(2 * jq) * 2 + 0], sA);
            atomicAdd(&sStat[(2 * jq) * 2 + 1], qA);
            atomicAdd(&sStat[(2 * jq + 1) * 2 + 0], sB);
            atomicAdd(&sStat[(2 * jq + 1) * 2 + 1], qB);
        }
    }
    __syncthreads();
    if (t < 64) atomicAdd(&rep1[(blockIdx.x & (NREP - 1)) * 64 + t], sStat[t]);
}

// ---------------------------------------------------------------------------
// K3: stage1.  2 rows/thread; reads x0 planes, writes x1 planes; fused stats.
// ---------------------------------------------------------------------------
__global__ __launch_bounds__(256, 2) void k_stage1(const float4* __restrict__ x0q,
        const float* __restrict__ W1,
        const float* __restrict__ A, const float* __restrict__ B,
        float4* __restrict__ x1q, float* __restrict__ rep2) {
    __shared__ float sW[32 * 64];
    __shared__ float sAB[128];
    __shared__ float sStat[64];
    const int t = threadIdx.x;
    for (int i = t; i < 32 * 64 / 4; i += 256) ((float4*)sW)[i] = ((const float4*)W1)[i];
    if (t < 64) { sAB[t] = A[t]; sAB[64 + t] = B[t]; sStat[t] = 0.f; }
    __syncthreads();

    const int lane = t & 63;
    const int b0 = blockIdx.x * 512;
    const int rowA = b0 + t;
    const int rowB = b0 + 256 + t;
    const bool validA = rowA < NVV;
    const bool validB = rowB < NVV;
    const int rA = validA ? rowA : NVV - 1;
    const int rB = validB ? rowB : NVV - 1;
    float vA[64], vB[64];
    #pragma unroll
    for (int k4 = 0; k4 < 16; ++k4) {
        const float4 uA = x0q[(size_t)k4 * NVV + rA];
        const float4 uB = x0q[(size_t)k4 * NVV + rB];
        const float4 a4 = *(const float4*)&sAB[k4 * 4];
        const float4 b4 = *(const float4*)&sAB[64 + k4 * 4];
        vA[4 * k4 + 0] = fmaxf(fmaf(uA.x, a4.x, b4.x), 0.f);
        vA[4 * k4 + 1] = fmaxf(fmaf(uA.y, a4.y, b4.y), 0.f);
        vA[4 * k4 + 2] = fmaxf(fmaf(uA.z, a4.z, b4.z), 0.f);
        vA[4 * k4 + 3] = fmaxf(fmaf(uA.w, a4.w, b4.w), 0.f);
        vB[4 * k4 + 0] = fmaxf(fmaf(uB.x, a4.x, b4.x), 0.f);
        vB[4 * k4 + 1] = fmaxf(fmaf(uB.y, a4.y, b4.y), 0.f);
        vB[4 * k4 + 2] = fmaxf(fmaf(uB.z, a4.z, b4.z), 0.f);
        vB[4 * k4 + 3] = fmaxf(fmaf(uB.w, a4.w, b4.w), 0.f);
    }
    #pragma unroll
    for (int jq = 0; jq < 8; ++jq) {
        float a0 = 0.f, a1 = 0.f, a2 = 0.f, a3 = 0.f;
        float c0 = 0.f, c1 = 0.f, c2 = 0.f, c3 = 0.f;
        #pragma unroll
        for (int k4 = 0; k4 < 16; ++k4) {
            const float vA0 = vA[4 * k4], vA1 = vA[4 * k4 + 1], vA2 = vA[4 * k4 + 2], vA3 = vA[4 * k4 + 3];
            const float vB0 = vB[4 * k4], vB1 = vB[4 * k4 + 1], vB2 = vB[4 * k4 + 2], vB3 = vB[4 * k4 + 3];
            const float4 w0 = *(const float4*)&sW[(jq * 4 + 0) * 64 + k4 * 4];
            const float4 w1 = *(const float4*)&sW[(jq * 4 + 1) * 64 + k4 * 4];
            a0 = fmaf(vA0, w0.x, fmaf(vA1, w0.y, fmaf(vA2, w0.z, fmaf(vA3, w0.w, a0))));
            a1 = fmaf(vA0, w1.x, fmaf(vA1, w1.y, fmaf(vA2, w1.z, fmaf(vA3, w1.w, a1))));
            c0 = fmaf(vB0, w0.x, fmaf(vB1, w0.y, fmaf(vB2, w0.z, fmaf(vB3, w0.w, c0))));
            c1 = fmaf(vB0, w1.x, fmaf(vB1, w1.y, fmaf(vB2, w1.z, fmaf(vB3, w1.w, c1))));
            const float4 w2 = *(const float4*)&sW[(jq * 4 + 2) * 64 + k4 * 4];
            const float4 w3 = *(const float4*)&sW[(jq * 4 + 3) * 64 + k4 * 4];
            a2 = fmaf(vA0, w2.x, fmaf(vA1, w2.y, fmaf(vA2, w2.z, fmaf(vA3, w2.w, a2))));
            a3 = fmaf(vA0, w3.x, fmaf(vA1, w3.y, fmaf(vA2, w3.z, fmaf(vA3, w3.w, a3))));
            c2 = fmaf(vB0, w2.x, fmaf(vB1, w2.y, fmaf(vB2, w2.z, fmaf(vB3, w2.w, c2))));
            c3 = fmaf(vB0, w3.x, fmaf(vB1, w3.y, fmaf(vB2, w3.z, fmaf(vB3, w3.w, c3))));
        }
        if (validA) x1q[(size_t)jq * NVV + rowA] = make_float4(a0, a1, a2, a3);
        if (validB) x1q[(size_t)jq * NVV + rowB] = make_float4(c0, c1, c2, c3);
        float s0 = (validA ? a0 : 0.f) + (validB ? c0 : 0.f);
        float q0 = (validA ? a0 * a0 : 0.f) + (validB ? c0 * c0 : 0.f);
        float s1 = (validA ? a1 : 0.f) + (validB ? c1 : 0.f);
        float q1 = (validA ? a1 * a1 : 0.f) + (validB ? c1 * c1 : 0.f);
        float s2 = (validA ? a2 : 0.f) + (validB ? c2 : 0.f);
        float q2 = (validA ? a2 * a2 : 0.f) + (validB ? c2 * c2 : 0.f);
        float s3 = (validA ? a3 : 0.f) + (validB ? c3 : 0.f);
        float q3 = (validA ? a3 * a3 : 0.f) + (validB ? c3 * c3 : 0.f);
        #pragma unroll
        for (int d = 1; d < 64; d <<= 1) {
            s0 += __shfl_xor(s0, d); q0 += __shfl_xor(q0, d);
            s1 += __shfl_xor(s1, d); q1 += __shfl_xor(q1, d);
            s2 += __shfl_xor(s2, d); q2 += __shfl_xor(q2, d);
            s3 += __shfl_xor(s3, d); q3 += __shfl_xor(q3, d);
        }
        if (lane == 0) {
            atomicAdd(&sStat[(jq * 4 + 0) * 2 + 0], s0); atomicAdd(&sStat[(jq * 4 + 0) * 2 + 1], q0);
            atomicAdd(&sStat[(jq * 4 + 1) * 2 + 0], s1); atomicAdd(&sStat[(jq * 4 + 1) * 2 + 1], q1);
            atomicAdd(&sStat[(jq * 4 + 2) * 2 + 0], s2); atomicAdd(&sStat[(jq * 4 + 2) * 2 + 1], q2);
            atomicAdd(&sStat[(jq * 4 + 3) * 2 + 0], s3); atomicAdd(&sStat[(jq * 4 + 3) * 2 + 1], q3);
        }
    }
    __syncthreads();
    if (t < 64) atomicAdd(&rep2[(blockIdx.x & (NREP - 1)) * 64 + t], sStat[t]);
}

// ---------------------------------------------------------------------------
// K4: stage2.  Reads x1 planes, writes x2 row-major [NV,8].
// ---------------------------------------------------------------------------
__global__ __launch_bounds__(256, 4) void k_stage2(const float4* __restrict__ x1q,
        const float* __restrict__ W2,
        const float* __restrict__ A, const float* __restrict__ B,
        float* __restrict__ x2) {
    __shared__ float sW[8 * 32];
    __shared__ float sAB[64];
    const int t = threadIdx.x;
    if (t < 64) ((float4*)sW)[t] = ((const float4*)W2)[t];
    if (t < 32) { sAB[t] = A[t]; sAB[32 + t] = B[t]; }
    __syncthreads();

    const int row = blockIdx.x * 256 + t;
    const bool valid = row < NVV;
    const int r = valid ? row : NVV - 1;
    float v[32];
    #pragma unroll
    for (int k4 = 0; k4 < 8; ++k4) {
        const float4 u = x1q[(size_t)k4 * NVV + r];
        const float4 a4 = *(const float4*)&sAB[k4 * 4];
        const float4 b4 = *(const float4*)&sAB[32 + k4 * 4];
        v[4 * k4 + 0] = fmaxf(fmaf(u.x, a4.x, b4.x), 0.f);
        v[4 * k4 + 1] = fmaxf(fmaf(u.y, a4.y, b4.y), 0.f);
        v[4 * k4 + 2] = fmaxf(fmaf(u.z, a4.z, b4.z), 0.f);
        v[4 * k4 + 3] = fmaxf(fmaf(u.w, a4.w, b4.w), 0.f);
    }
    #pragma unroll
    for (int jq = 0; jq < 2; ++jq) {
        float a0 = 0.f, a1 = 0.f, a2 = 0.f, a3 = 0.f;
        #pragma unroll
        for (int k4 = 0; k4 < 8; ++k4) {
            const float4 w0 = *(const float4*)&sW[(jq * 4 + 0) * 32 + k4 * 4];
            const float4 w1 = *(const float4*)&sW[(jq * 4 + 1) * 32 + k4 * 4];
            const float4 w2 = *(const float4*)&sW[(jq * 4 + 2) * 32 + k4 * 4];
            const float4 w3 = *(const float4*)&sW[(jq * 4 + 3) * 32 + k4 * 4];
            const float v0 = v[4 * k4], v1 = v[4 * k4 + 1], v2 = v[4 * k4 + 2], v3 = v[4 * k4 + 3];
            a0 = fmaf(v0, w0.x, fmaf(v1, w0.y, fmaf(v2, w0.z, fmaf(v3, w0.w, a0))));
            a1 = fmaf(v0, w1.x, fmaf(v1, w1.y, fmaf(v2, w1.z, fmaf(v3, w1.w, a1))));
            a2 = fmaf(v0, w2.x, fmaf(v1, w2.y, fmaf(v2, w2.z, fmaf(v3, w2.w, a2))));
            a3 = fmaf(v0, w3.x, fmaf(v1, w3.y, fmaf(v2, w3.z, fmaf(v3, w3.w, a3))));
        }
        if (valid) *(float4*)(x2 + (size_t)row * 8 + jq * 4) = make_float4(a0, a1, a2, a3);
    }
}

// ---------------------------------------------------------------------------
// K5: per-position gather + max-normalize + delta weights + classify via proj.
// ---------------------------------------------------------------------------
__global__ __launch_bounds__(256, 4) void k_final(const int* __restrict__ idx,
        const float* __restrict__ bary, const float* __restrict__ x2,
        const float* __restrict__ proj, const float* __restrict__ gamma,
        const float* __restrict__ beta, const float* __restrict__ dWw,
        const float* __restrict__ dWb, const float* __restrict__ clsb,
        float* __restrict__ out) {
    const int p = blockIdx.x * 256 + threadIdx.x;
    if (p >= PCNT) return;
    const int4 iv = *(const int4*)(idx + (size_t)p * 4);
    const float4 bv = *(const float4*)(bary + (size_t)p * 4);
    const int ids[4] = {iv.x, iv.y, iv.z, iv.w};
    const float bb[4] = {bv.x, bv.y, bv.z, bv.w};
    float g[4][8];
    #pragma unroll
    for (int vtx = 0; vtx < 4; ++vtx) {
        const float* s = x2 + (size_t)ids[vtx] * 8;
        const float4 u0 = *(const float4*)(s);
        const float4 u1 = *(const float4*)(s + 4);
        g[vtx][0] = u0.x; g[vtx][1] = u0.y; g[vtx][2] = u0.z; g[vtx][3] = u0.w;
        g[vtx][4] = u1.x; g[vtx][5] = u1.y; g[vtx][6] = u1.z; g[vtx][7] = u1.w;
    }
    float sub[9];
    #pragma unroll
    for (int j = 0; j < 8; ++j) {
        const float mx = fmaxf(fmaxf(g[0][j], g[1][j]), fmaxf(g[2][j], g[3][j]));
        sub[j] = fmaf(gamma[j], mx, beta[j]);
    }
    {
        const float mx8 = fmaxf(fmaxf(bb[0], bb[1]), fmaxf(bb[2], bb[3]));
        sub[8] = fmaf(gamma[8], mx8, beta[8]);
    }
    float wv4[4];
    #pragma unroll
    for (int vtx = 0; vtx < 4; ++vtx) {
        float dw = dWb[0];
        #pragma unroll
        for (int j = 0; j < 8; ++j) dw = fmaf(g[vtx][j] - sub[j], dWw[j], dw);
        dw = fmaf(bb[vtx] - sub[8], dWw[8], dw);
        wv4[vtx] = bb[vtx] + dw;
    }
    float acc[20];
    #pragma unroll
    for (int c = 0; c < 20; ++c) acc[c] = clsb[c];
    #pragma unroll
    for (int vtx = 0; vtx < 4; ++vtx) {
        const float* pr = proj + (size_t)ids[vtx] * 20;
        const float wgt = wv4[vtx];
        #pragma unroll
        for (int cq = 0; cq < 5; ++cq) {
            const float4 u = *(const float4*)(pr + cq * 4);
            acc[cq * 4 + 0] = fmaf(wgt, u.x, acc[cq * 4 + 0]);
            acc[cq * 4 + 1] = fmaf(wgt, u.y, acc[cq * 4 + 1]);
            acc[cq * 4 + 2] = fmaf(wgt, u.z, acc[cq * 4 + 2]);
            acc[cq * 4 + 3] = fmaf(wgt, u.w, acc[cq * 4 + 3]);
        }
    }
    float* o = out + (size_t)p * 20;
    #pragma unroll
    for (int cq = 0; cq < 5; ++cq)
        *(float4*)(o + cq * 4) = make_float4(acc[cq * 4 + 0], acc[cq * 4 + 1],
                                             acc[cq * 4 + 2], acc[cq * 4 + 3]);
}

// ---------------------------------------------------------------------------
extern "C" void kernel_launch(void* const* d_in, const int* in_sizes, int n_in,
                              void* d_out, int out_size, void* d_ws, size_t ws_size,
                              hipStream_t stream) {
    const float* lv   = (const float*)d_in[0];
    // d_in[1] = positions — unused by the reference
    const int*   idx  = (const int*)d_in[2];
    const float* bary = (const float*)d_in[3];
    const float* gn0w = (const float*)d_in[4];
    const float* gn0b = (const float*)d_in[5];
    const float* W0   = (const float*)d_in[6];
    const float* gn1w = (const float*)d_in[7];
    const float* gn1b = (const float*)d_in[8];
    const float* W1   = (const float*)d_in[9];
    const float* gn2w = (const float*)d_in[10];
    const float* gn2b = (const float*)d_in[11];
    const float* W2   = (const float*)d_in[12];
    const float* gamma= (const float*)d_in[13];
    const float* beta = (const float*)d_in[14];
    const float* dWw  = (const float*)d_in[15];
    const float* dWb  = (const float*)d_in[16];
    const float* clsW = (const float*)d_in[17];
    const float* clsb = (const float*)d_in[18];
    float* out = (float*)d_out;

    float* w = (float*)d_ws;
    float* rep0 = w;                  // 8*64
    float* rep1 = w + 512;            // 8*64
    float* rep2 = w + 1024;           // 8*64
    float* A0 = w + 1536; float* B0 = w + 1600;
    float* A1 = w + 1664; float* B1 = w + 1728;
    float* A2 = w + 1792; float* B2 = w + 1856;
    float*  proj = w + 2048;                         // NV*20 floats
    float4* x0q  = (float4*)(proj + (size_t)NVV * 20);   // 16*NV float4
    float4* x1q  = x0q + (size_t)16 * NVV;               // 8*NV float4
    float*  x2   = (float*)x0q;                          // reuse x0q after K3

    hipMemsetAsync(w, 0, 1536 * sizeof(float), stream);
    k_stats0<<<512, 256, 0, stream>>>(lv, rep0);
    k_finalize<<<1, 64, 0, stream>>>(rep0, gn0w, gn0b, A0, B0, 64, 1.f / (NVV * 2.f));
    k_stage0<<<586, 256, 0, stream>>>(lv, W0, clsW, A0, B0, x0q, proj, rep1);
    k_finalize<<<1, 64, 0, stream>>>(rep1, gn1w, gn1b, A1, B1, 64, 1.f / (NVV * 2.f));
    k_stage1<<<586, 256, 0, stream>>>(x0q, W1, A1, B1, x1q, rep2);
    k_finalize<<<1, 32, 0, stream>>>(rep2, gn2w, gn2b, A2, B2, 32, 1.f / (float)NVV);
    k_stage2<<<1172, 256, 0, stream>>>(x1q, W2, A2, B2, x2);
    k_final<<<1954, 256, 0, stream>>>(idx, bary, x2, proj, gamma, beta, dWw, dWb, clsb, out);
}